// Round 7
// baseline (321.852 us; speedup 1.0000x reference)
//
#include <hip/hip_runtime.h>
#include <math.h>

#define B_  4
#define T_  2048
#define C_  1024
#define NH_ 16
#define HS_ 64
#define M_  (B_ * T_)          // 8192
#define BH_ (B_ * NH_)         // 64

typedef __bf16 bf16_t;
typedef __bf16 bf16x8 __attribute__((ext_vector_type(8)));
typedef float  f32x4  __attribute__((ext_vector_type(4)));

__device__ __forceinline__ f32x4 mfma16(bf16x8 a, bf16x8 b, f32x4 c) {
    return __builtin_amdgcn_mfma_f32_16x16x32_bf16(a, b, c, 0, 0, 0);
}

// async global->LDS, 16B per lane (dest = wave-uniform base + lane*16).
#define GLOAD16(gp, lp) __builtin_amdgcn_global_load_lds( \
    (const __attribute__((address_space(1))) void*)(gp),  \
    (__attribute__((address_space(3))) void*)(lp), 16, 0, 0)

// raw barrier + compile-time pinning (no vmcnt drain, unlike __syncthreads)
#define SBAR() do { asm volatile("" ::: "memory"); \
                    __builtin_amdgcn_s_barrier(); \
                    __builtin_amdgcn_sched_barrier(0); } while (0)
// rule #18: lgkmcnt asm needs a following sched_barrier(0)
#define LGKM0() do { asm volatile("s_waitcnt lgkmcnt(0)" ::: "memory"); \
                     __builtin_amdgcn_sched_barrier(0); } while (0)
// counted vmcnt: allow the newest 6 loads (tile t+2's stages) to stay in flight
#define VMCNT6() do { asm volatile("s_waitcnt vmcnt(6)" ::: "memory"); \
                      __builtin_amdgcn_sched_barrier(0); } while (0)

// ---------------- prep kernels ----------------

__global__ void cvt_x(const float* __restrict__ x, bf16_t* __restrict__ xb) {
    int i = blockIdx.x * blockDim.x + threadIdx.x;
    const float4* src = reinterpret_cast<const float4*>(x);
    float4 u = src[2 * i], v = src[2 * i + 1];
    bf16x8 o;
    o[0] = (bf16_t)u.x; o[1] = (bf16_t)u.y; o[2] = (bf16_t)u.z; o[3] = (bf16_t)u.w;
    o[4] = (bf16_t)v.x; o[5] = (bf16_t)v.y; o[6] = (bf16_t)v.z; o[7] = (bf16_t)v.w;
    *reinterpret_cast<bf16x8*>(xb + (size_t)i * 8) = o;
}

__global__ void wtrans(const float* __restrict__ W, bf16_t* __restrict__ Wt) {
    __shared__ float tile[32][33];
    int bx = blockIdx.x, by = blockIdx.y;
    int tx = threadIdx.x, ty = threadIdx.y;
    #pragma unroll
    for (int j = 0; j < 4; ++j)
        tile[ty + j * 8][tx] = W[(size_t)(by * 32 + ty + j * 8) * 1024 + bx * 32 + tx];
    __syncthreads();
    #pragma unroll
    for (int j = 0; j < 4; ++j)
        Wt[(size_t)(bx * 32 + ty + j * 8) * 1024 + by * 32 + tx] = (bf16_t)tile[tx][ty + j * 8];
}

__global__ void rope_tab(float* __restrict__ cs, float* __restrict__ sn) {
    int idx = blockIdx.x * blockDim.x + threadIdx.x;
    int t = idx >> 5, j = idx & 31;
    float inv = 1.0f / powf(10000.0f, ((float)(2 * j)) / 64.0f);
    float ang = (float)t * inv;
    cs[idx] = cosf(ang);
    sn[idx] = sinf(ang);
}

// ---------------- 8-phase GEMM core (BM=256, BN=128, BK=64, 8 waves 4Mx2N) ----------------
// 3 LDS buffers; compute tile t from buf[t%3] while staging tile t+2 into buf[(t+2)%3].
// Per tile: 4 phases (one A-frag each, 8 MFMA/phase); the 6 stage-loads of tile t+2
// are spread over the phases; one counted vmcnt(6) per tile (never 0 in the loop).
// LDS swizzle (verified R5): LDS[row][ch] = G[row][ch ^ (row&7)], 16B chunks, 8/row.
__device__ __forceinline__ void gemm8_core(
    const bf16_t* __restrict__ Aptr, const bf16_t* __restrict__ Bptr,
    int mbase, int nbase, f32x4 (&acc)[4][4]) {
    __shared__ __align__(16) bf16_t Ab[3][256 * 64];
    __shared__ __align__(16) bf16_t Bb[3][128 * 64];
    int tid = threadIdx.x;
    int lane = tid & 63, w = tid >> 6;
    int rr = lane & 15, g = lane >> 4, r7 = rr & 7;
    int wm = (w >> 1) * 64, wn = (w & 1) * 64;
    int rA = tid >> 3, cS = (tid & 7) ^ (rA & 7);
    int dOff = rA * 64 + (tid & 7) * 8;
    const bf16_t* As = Aptr + (size_t)(mbase + rA) * 1024 + cS * 8;
    const bf16_t* Bs = Bptr + (size_t)(nbase + rA) * 1024 + cS * 8;
    int co0 = (g ^ r7) * 8, co1 = ((4 + g) ^ r7) * 8;

    // prologue: stage tiles 0 and 1 (6 loads each)
    GLOAD16(As,                   Ab[0] + dOff);
    GLOAD16(As + 64 * 1024,       Ab[0] + 4096 + dOff);
    GLOAD16(As + 128 * 1024,      Ab[0] + 8192 + dOff);
    GLOAD16(As + 192 * 1024,      Ab[0] + 12288 + dOff);
    GLOAD16(Bs,                   Bb[0] + dOff);
    GLOAD16(Bs + 64 * 1024,       Bb[0] + 4096 + dOff);
    GLOAD16(As + 64,              Ab[1] + dOff);
    GLOAD16(As + 64 + 64 * 1024,  Ab[1] + 4096 + dOff);
    GLOAD16(As + 64 + 128 * 1024, Ab[1] + 8192 + dOff);
    GLOAD16(As + 64 + 192 * 1024, Ab[1] + 12288 + dOff);
    GLOAD16(Bs + 64,              Bb[1] + dOff);
    GLOAD16(Bs + 64 + 64 * 1024,  Bb[1] + 4096 + dOff);
    VMCNT6();   // tile 0's 6 loads retired
    SBAR();

    int c = 0;
    #pragma unroll 1
    for (int t = 0; t < 16; ++t) {
        bf16_t* pAc = Ab[c];
        bf16_t* pBc = Bb[c];
        int c2 = c + 2; if (c2 >= 3) c2 -= 3;
        bf16_t* pAn = Ab[c2];
        bf16_t* pBn = Bb[c2];
        int k2 = (t + 2 < 16) ? (t + 2) : 15;   // clamped re-stage lands in a dead buffer
        const bf16_t* As2 = As + k2 * 64;
        const bf16_t* Bs2 = Bs + k2 * 64;
        bf16x8 bfr[4][2], av0, av1;

        // ---- P0: all B-frags + A-frag 0; stage A halves 0,1 of tile t+2
        #pragma unroll
        for (int ni = 0; ni < 4; ++ni) {
            bfr[ni][0] = *(const bf16x8*)&pBc[(wn + ni * 16 + rr) * 64 + co0];
            bfr[ni][1] = *(const bf16x8*)&pBc[(wn + ni * 16 + rr) * 64 + co1];
        }
        av0 = *(const bf16x8*)&pAc[(wm + rr) * 64 + co0];
        av1 = *(const bf16x8*)&pAc[(wm + rr) * 64 + co1];
        GLOAD16(As2,             pAn + dOff);
        GLOAD16(As2 + 64 * 1024, pAn + 4096 + dOff);
        SBAR(); LGKM0();
        __builtin_amdgcn_s_setprio(1);
        #pragma unroll
        for (int ni = 0; ni < 4; ++ni) acc[0][ni] = mfma16(av0, bfr[ni][0], acc[0][ni]);
        #pragma unroll
        for (int ni = 0; ni < 4; ++ni) acc[0][ni] = mfma16(av1, bfr[ni][1], acc[0][ni]);
        __builtin_amdgcn_s_setprio(0);
        SBAR();

        // ---- P1: A-frag 1; stage A halves 2,3
        av0 = *(const bf16x8*)&pAc[(wm + 16 + rr) * 64 + co0];
        av1 = *(const bf16x8*)&pAc[(wm + 16 + rr) * 64 + co1];
        GLOAD16(As2 + 128 * 1024, pAn + 8192 + dOff);
        GLOAD16(As2 + 192 * 1024, pAn + 12288 + dOff);
        SBAR(); LGKM0();
        __builtin_amdgcn_s_setprio(1);
        #pragma unroll
        for (int ni = 0; ni < 4; ++ni) acc[1][ni] = mfma16(av0, bfr[ni][0], acc[1][ni]);
        #pragma unroll
        for (int ni = 0; ni < 4; ++ni) acc[1][ni] = mfma16(av1, bfr[ni][1], acc[1][ni]);
        __builtin_amdgcn_s_setprio(0);
        SBAR();

        // ---- P2: A-frag 2; stage B half 0
        av0 = *(const bf16x8*)&pAc[(wm + 32 + rr) * 64 + co0];
        av1 = *(const bf16x8*)&pAc[(wm + 32 + rr) * 64 + co1];
        GLOAD16(Bs2, pBn + dOff);
        SBAR(); LGKM0();
        __builtin_amdgcn_s_setprio(1);
        #pragma unroll
        for (int ni = 0; ni < 4; ++ni) acc[2][ni] = mfma16(av0, bfr[ni][0], acc[2][ni]);
        #pragma unroll
        for (int ni = 0; ni < 4; ++ni) acc[2][ni] = mfma16(av1, bfr[ni][1], acc[2][ni]);
        __builtin_amdgcn_s_setprio(0);
        SBAR();

        // ---- P3: A-frag 3; stage B half 1; counted vmcnt gate for tile t+1
        av0 = *(const bf16x8*)&pAc[(wm + 48 + rr) * 64 + co0];
        av1 = *(const bf16x8*)&pAc[(wm + 48 + rr) * 64 + co1];
        GLOAD16(Bs2 + 64 * 1024, pBn + 4096 + dOff);
        VMCNT6();   // 12 outstanding -> 6: tile t+1's stages retired, t+2's stay in flight
        SBAR(); LGKM0();
        __builtin_amdgcn_s_setprio(1);
        #pragma unroll
        for (int ni = 0; ni < 4; ++ni) acc[3][ni] = mfma16(av0, bfr[ni][0], acc[3][ni]);
        #pragma unroll
        for (int ni = 0; ni < 4; ++ni) acc[3][ni] = mfma16(av1, bfr[ni][1], acc[3][ni]);
        __builtin_amdgcn_s_setprio(0);
        SBAR();

        c = (c + 1 == 3) ? 0 : c + 1;
    }
}

// ---------------- QKV GEMM ----------------
__global__ __launch_bounds__(512, 2) void gemm_qkv(
    const bf16_t* __restrict__ Aptr, const bf16_t* __restrict__ Bptr,
    const float* __restrict__ bq, const float* __restrict__ bk, const float* __restrict__ bv,
    bf16_t* __restrict__ outq, bf16_t* __restrict__ outk, bf16_t* __restrict__ outvt) {
    // bijective XCD swizzle: nwg=768, cpx=96
    int lin = blockIdx.y * 24 + blockIdx.x;
    int swz = (lin & 7) * 96 + (lin >> 3);
    int bx = swz % 24, by = swz / 24;
    int mbase = by * 256, nbase = bx * 128;
    f32x4 acc[4][4] = {};
    gemm8_core(Aptr, Bptr, mbase, nbase, acc);
    int lane = threadIdx.x & 63, w = threadIdx.x >> 6;
    int rr = lane & 15, g = lane >> 4;
    int wm = (w >> 1) * 64, wn = (w & 1) * 64;
    #pragma unroll
    for (int ni = 0; ni < 4; ++ni) {
        int n = nbase + wn + ni * 16 + rr;
        int sel = n >> 10, nn = n & 1023, h = nn >> 6, d = nn & 63;
        float bias = (sel == 0) ? bq[nn] : (sel == 1) ? bk[nn] : bv[nn];
        #pragma unroll
        for (int mi = 0; mi < 4; ++mi) {
            #pragma unroll
            for (int j = 0; j < 4; ++j) {
                int mrow = mbase + wm + mi * 16 + g * 4 + j;
                int bI = mrow >> 11, tt = mrow & 2047;
                float val = acc[mi][ni][j] + bias;
                size_t bh = (size_t)(bI * 16 + h);
                if (sel == 0)      outq[(bh * 2048 + tt) * 64 + d] = (bf16_t)val;
                else if (sel == 1) outk[(bh * 2048 + tt) * 64 + d] = (bf16_t)val;
                else               outvt[(bh * 64 + d) * 2048 + tt] = (bf16_t)val;
            }
        }
    }
}

// ---------------- projection GEMM ----------------
__global__ __launch_bounds__(512, 2) void gemm_proj(
    const bf16_t* __restrict__ Aptr, const bf16_t* __restrict__ Bptr,
    const float* __restrict__ bp, float* __restrict__ out) {
    // bijective XCD swizzle: nwg=256, cpx=32
    int lin = blockIdx.y * 8 + blockIdx.x;
    int swz = (lin & 7) * 32 + (lin >> 3);
    int bx = swz % 8, by = swz / 8;
    int mbase = by * 256, nbase = bx * 128;
    f32x4 acc[4][4] = {};
    gemm8_core(Aptr, Bptr, mbase, nbase, acc);
    int lane = threadIdx.x & 63, w = threadIdx.x >> 6;
    int rr = lane & 15, g = lane >> 4;
    int wm = (w >> 1) * 64, wn = (w & 1) * 64;
    #pragma unroll
    for (int ni = 0; ni < 4; ++ni) {
        int n = nbase + wn + ni * 16 + rr;
        float bias = bp[n];
        #pragma unroll
        for (int mi = 0; mi < 4; ++mi) {
            #pragma unroll
            for (int j = 0; j < 4; ++j) {
                int mrow = mbase + wm + mi * 16 + g * 4 + j;
                out[(size_t)mrow * 1024 + n] = acc[mi][ni][j] + bias;
            }
        }
    }
}

// ---------------- RoPE on q,k (bf16 in-place) ----------------
__global__ void rope_qk(bf16_t* __restrict__ q, bf16_t* __restrict__ k,
                        const float* __restrict__ cs, const float* __restrict__ sn) {
    int idx = blockIdx.x * blockDim.x + threadIdx.x;
    int seg = idx & 7;
    int t = (idx >> 3) & 2047;
    int bh = idx >> 14;
    float4 cc = *reinterpret_cast<const float4*>(cs + (t << 5) + seg * 4);
    float4 ss = *reinterpret_cast<const float4*>(sn + (t << 5) + seg * 4);
    size_t base = (((size_t)bh << 11) + t) * 64 + seg * 8;
    {
        bf16x8 v = *reinterpret_cast<bf16x8*>(q + base);
        bf16x8 o;
        o[0] = (bf16_t)((float)v[0] * cc.x - (float)v[1] * ss.x);
        o[1] = (bf16_t)((float)v[0] * ss.x + (float)v[1] * cc.x);
        o[2] = (bf16_t)((float)v[2] * cc.y - (float)v[3] * ss.y);
        o[3] = (bf16_t)((float)v[2] * ss.y + (float)v[3] * cc.y);
        o[4] = (bf16_t)((float)v[4] * cc.z - (float)v[5] * ss.z);
        o[5] = (bf16_t)((float)v[4] * ss.z + (float)v[5] * cc.z);
        o[6] = (bf16_t)((float)v[6] * cc.w - (float)v[7] * ss.w);
        o[7] = (bf16_t)((float)v[6] * ss.w + (float)v[7] * cc.w);
        *reinterpret_cast<bf16x8*>(q + base) = o;
    }
    {
        bf16x8 v = *reinterpret_cast<bf16x8*>(k + base);
        bf16x8 o;
        o[0] = (bf16_t)((float)v[0] * cc.x - (float)v[1] * ss.x);
        o[1] = (bf16_t)((float)v[0] * ss.x + (float)v[1] * cc.x);
        o[2] = (bf16_t)((float)v[2] * cc.y - (float)v[3] * ss.y);
        o[3] = (bf16_t)((float)v[2] * ss.y + (float)v[3] * cc.y);
        o[4] = (bf16_t)((float)v[4] * cc.z - (float)v[5] * ss.z);
        o[5] = (bf16_t)((float)v[4] * ss.z + (float)v[5] * cc.z);
        o[6] = (bf16_t)((float)v[6] * cc.w - (float)v[7] * ss.w);
        o[7] = (bf16_t)((float)v[6] * ss.w + (float)v[7] * cc.w);
        *reinterpret_cast<bf16x8*>(k + base) = o;
    }
}

// ---------------- flash attention (unchanged from R4/R5 — verified) ----------------
__global__ __launch_bounds__(256) void attn(
    const bf16_t* __restrict__ q, const bf16_t* __restrict__ k,
    const bf16_t* __restrict__ vt, bf16_t* __restrict__ y) {
    __shared__ __align__(16) bf16_t Kb[2][64 * 64];
    __shared__ __align__(16) bf16_t Vb[2][64 * 64];
    int tid = threadIdx.x;
    int lane = tid & 63, w = tid >> 6;
    int rr = lane & 15, g = lane >> 4;
    int bid = blockIdx.x;
    int xcd = bid & 7, idx = bid >> 3;
    int bh = xcd * 8 + (idx >> 4);
    int xp = idx & 15;
    const bf16_t* qh = q + (size_t)bh * T_ * HS_;
    const bf16_t* kh = k + (size_t)bh * T_ * HS_;
    const bf16_t* vh = vt + (size_t)bh * HS_ * T_;
    int bI = bh >> 4, h = bh & 15;
    int s0 = ((rr >> 2) << 3) + (rr & 3);
    const float SC = 0.125f * 1.44269504088896f;

    int i2a = tid, i2b = tid + 256;
    int rwa = i2a >> 3, rwb = i2b >> 3;
    int swKa = (rwa & 3) | (((rwa >> 3) & 1) << 2);
    int swKb = (rwb & 3) | (((rwb >> 3) & 1) << 2);
    int cKa = (i2a & 7) ^ swKa, cKb = (i2b & 7) ^ swKb;
    int cVa = (i2a & 7) ^ (rwa & 7), cVb = (i2b & 7) ^ (rwb & 7);

    #pragma unroll 1
    for (int pass = 0; pass < 2; ++pass) {
        int qt = pass ? (31 - xp) : xp;
        int qbase = qt * 64;
        int qrow = qbase + w * 16 + rr;
        bf16x8 qf0 = *reinterpret_cast<const bf16x8*>(qh + (size_t)qrow * 64 + g * 8);
        bf16x8 qf1 = *reinterpret_cast<const bf16x8*>(qh + (size_t)qrow * 64 + 32 + g * 8);
        float mrun = -1e30f, lsum = 0.f;
        f32x4 oacc[4] = {};
        int nt = qt + 1;
        GLOAD16(kh + (size_t)rwa * 64 + cKa * 8, &Kb[0][i2a * 8]);
        GLOAD16(kh + (size_t)rwb * 64 + cKb * 8, &Kb[0][i2b * 8]);
        GLOAD16(vh + (size_t)rwa * 2048 + cVa * 8, &Vb[0][i2a * 8]);
        GLOAD16(vh + (size_t)rwb * 2048 + cVb * 8, &Vb[0][i2b * 8]);
        __syncthreads();
        int cur = 0;
        #pragma unroll 1
        for (int t = 0; t < nt; ++t) {
            if (t + 1 < nt) {
                int kv1 = (t + 1) * 64;
                GLOAD16(kh + (size_t)(kv1 + rwa) * 64 + cKa * 8, &Kb[cur ^ 1][i2a * 8]);
                GLOAD16(kh + (size_t)(kv1 + rwb) * 64 + cKb * 8, &Kb[cur ^ 1][i2b * 8]);
                GLOAD16(vh + (size_t)rwa * 2048 + kv1 + cVa * 8, &Vb[cur ^ 1][i2a * 8]);
                GLOAD16(vh + (size_t)rwb * 2048 + kv1 + cVb * 8, &Vb[cur ^ 1][i2b * 8]);
            }
            int kv0 = t * 64;
            f32x4 st[4] = {};
            #pragma unroll
            for (int s = 0; s < 2; ++s) {
                #pragma unroll
                for (int p = 0; p < 2; ++p) {
                    int row = s * 32 + s0 + p * 4;
                    int sw = (row & 3) | (((row >> 3) & 1) << 2);
                    bf16x8 k0 = *(const bf16x8*)&Kb[cur][row * 64 + ((g ^ sw) * 8)];
                    bf16x8 k1 = *(const bf16x8*)&Kb[cur][row * 64 + (((4 + g) ^ sw) * 8)];
                    st[2 * s + p] = mfma16(k0, qf0, st[2 * s + p]);
                    st[2 * s + p] = mfma16(k1, qf1, st[2 * s + p]);
                }
            }
            float sv[16];
            #pragma unroll
            for (int s = 0; s < 2; ++s)
                #pragma unroll
                for (int p = 0; p < 2; ++p)
                    #pragma unroll
                    for (int j = 0; j < 4; ++j)
                        sv[s * 8 + p * 4 + j] = st[2 * s + p][j] * SC;
            if (t == nt - 1) {
                #pragma unroll
                for (int i = 0; i < 16; ++i) {
                    int kvi = kv0 + (i >> 3) * 32 + g * 8 + (i & 7);
                    if (kvi > qrow) sv[i] = -1e30f;
                }
            }
            float pmax = sv[0];
            #pragma unroll
            for (int i = 1; i < 16; ++i) pmax = fmaxf(pmax, sv[i]);
            pmax = fmaxf(pmax, __shfl_xor(pmax, 16));
            pmax = fmaxf(pmax, __shfl_xor(pmax, 32));
            float mnew = fmaxf(mrun, pmax);
            float fac = __builtin_amdgcn_exp2f(mrun - mnew);
            float psum = 0.f;
            bf16x8 pf0, pf1;
            #pragma unroll
            for (int i = 0; i < 8; ++i) {
                float pe = __builtin_amdgcn_exp2f(sv[i] - mnew);
                psum += pe;
                pf0[i] = (bf16_t)pe;
            }
            #pragma unroll
            for (int i = 0; i < 8; ++i) {
                float pe = __builtin_amdgcn_exp2f(sv[8 + i] - mnew);
                psum += pe;
                pf1[i] = (bf16_t)pe;
            }
            psum += __shfl_xor(psum, 16);
            psum += __shfl_xor(psum, 32);
            lsum = lsum * fac + psum;
            mrun = mnew;
            #pragma unroll
            for (int ch = 0; ch < 4; ++ch) {
                #pragma unroll
                for (int j = 0; j < 4; ++j) oacc[ch][j] *= fac;
            }
            #pragma unroll
            for (int ch = 0; ch < 4; ++ch) {
                int row = ch * 16 + rr;
                bf16x8 v0 = *(const bf16x8*)&Vb[cur][row * 64 + ((g ^ (row & 7)) * 8)];
                bf16x8 v1 = *(const bf16x8*)&Vb[cur][row * 64 + (((4 + g) ^ (row & 7)) * 8)];
                oacc[ch] = mfma16(v0, pf0, oacc[ch]);
                oacc[ch] = mfma16(v1, pf1, oacc[ch]);
            }
            __syncthreads();
            cur ^= 1;
        }
        float inv = 1.0f / lsum;
        bf16_t* yrow = y + ((size_t)bI * 2048 + qrow) * 1024 + h * 64;
        #pragma unroll
        for (int ch = 0; ch < 4; ++ch) {
            union { bf16_t b[4]; short4 s4; } u;
            #pragma unroll
            for (int j = 0; j < 4; ++j) u.b[j] = (bf16_t)(oacc[ch][j] * inv);
            *reinterpret_cast<short4*>(yrow + ch * 16 + g * 4) = u.s4;
        }
    }
}

// ---------------- launch ----------------
extern "C" void kernel_launch(void* const* d_in, const int* in_sizes, int n_in,
                              void* d_out, int out_size, void* d_ws, size_t ws_size,
                              hipStream_t stream) {
    const float* x  = (const float*)d_in[0];
    const float* Wq = (const float*)d_in[1];
    const float* bq = (const float*)d_in[2];
    const float* Wk = (const float*)d_in[3];
    const float* bk = (const float*)d_in[4];
    const float* Wv = (const float*)d_in[5];
    const float* bv = (const float*)d_in[6];
    const float* Wp = (const float*)d_in[7];
    const float* bp = (const float*)d_in[8];
    float* out = (float*)d_out;

    char* p = (char*)d_ws;
    auto alloc = [&](size_t n) { char* r = p; p += (n + 255) & ~(size_t)255; return r; };
    bf16_t* xb    = (bf16_t*)alloc((size_t)M_ * C_ * 2);
    bf16_t* wtqkv = (bf16_t*)alloc((size_t)3 * C_ * C_ * 2);
    bf16_t* wtp   = (bf16_t*)alloc((size_t)C_ * C_ * 2);
    bf16_t* qb    = (bf16_t*)alloc((size_t)BH_ * T_ * HS_ * 2);
    bf16_t* kb    = (bf16_t*)alloc((size_t)BH_ * T_ * HS_ * 2);
    bf16_t* vtb   = (bf16_t*)alloc((size_t)BH_ * HS_ * T_ * 2);
    bf16_t* yb    = (bf16_t*)alloc((size_t)M_ * C_ * 2);
    float*  cs    = (float*)alloc((size_t)T_ * 32 * 4);
    float*  sn    = (float*)alloc((size_t)T_ * 32 * 4);

    cvt_x<<<4096, 256, 0, stream>>>(x, xb);
    wtrans<<<dim3(32, 32), dim3(32, 8), 0, stream>>>(Wq, wtqkv);
    wtrans<<<dim3(32, 32), dim3(32, 8), 0, stream>>>(Wk, wtqkv + (size_t)C_ * C_);
    wtrans<<<dim3(32, 32), dim3(32, 8), 0, stream>>>(Wv, wtqkv + (size_t)2 * C_ * C_);
    wtrans<<<dim3(32, 32), dim3(32, 8), 0, stream>>>(Wp, wtp);
    rope_tab<<<256, 256, 0, stream>>>(cs, sn);

    gemm_qkv<<<dim3(24, 32), 512, 0, stream>>>(xb, wtqkv, bq, bk, bv, qb, kb, vtb);
    rope_qk<<<4096, 256, 0, stream>>>(qb, kb, cs, sn);
    attn<<<1024, 256, 0, stream>>>(qb, kb, vtb, yb);
    gemm_proj<<<dim3(8, 32), 512, 0, stream>>>(yb, wtp, bp, out);
}